// Round 16
// baseline (329.297 us; speedup 1.0000x reference)
//
#include <hip/hip_runtime.h>
#include <hip/hip_bf16.h>
#include <stdint.h>

// Problem constants (B=8, S=8192, K=1024, N=1024, G=128)
#define M_DIM 65536
#define K_DIM 1024
#define N_DIM 1024
#define NGRP  8

#define P_BM 128                // panel rows per block
#define T_BN 128
#define T_BK 64
#define T_NKT (K_DIM / T_BK)    // 16
#define NNT   (N_DIM / T_BN)    // 8

typedef float f32x4 __attribute__((ext_vector_type(4)));
typedef int   ix4   __attribute__((ext_vector_type(4)));

// ---------------- prep: wd = w_q - w_zp (int8) [N][K], bias -> f32 ----------------
__global__ void prep_wd_kernel(const int* __restrict__ w_q,
                               const int* __restrict__ w_zp,
                               const int* __restrict__ bias_q,
                               const float* __restrict__ bias_scale,
                               int8_t* __restrict__ Wd,
                               float* __restrict__ bias_f) {
    const int n = blockIdx.x;       // 0..1023
    const int t = threadIdx.x;      // 0..255
    const int k0 = t * 4;
    const int g = k0 >> 7;
    const int zp = w_zp[n * NGRP + g];
    const int4 wq = *reinterpret_cast<const int4*>(w_q + (size_t)n * K_DIM + k0);
    union { int u; int8_t b[4]; } pk;
    pk.b[0] = (int8_t)(wq.x - zp);
    pk.b[1] = (int8_t)(wq.y - zp);
    pk.b[2] = (int8_t)(wq.z - zp);
    pk.b[3] = (int8_t)(wq.w - zp);
    *reinterpret_cast<int*>(Wd + (size_t)n * K_DIM + k0) = pk.u;
    if (t == 0) bias_f[n] = ((float)bias_q[n] - 128.0f) * bias_scale[n];
}

// ---------------- fused panel GEMM ----------------
// One block per mt (grid 512). Phase 1: quantize x[m0:m0+128, :] -> Apanel
// in LDS (128 KB, XOR-swizzled bo ^= (row&7)<<4; write pattern bank-uniform).
// Phase 2: for nt = 0..7, run the r9 inner loop with A read from the panel
// (no A staging) and B double-buffered via global_load_lds (r9 swizzle,
// 0-conflict r2-r15); per-tile exact group combine facc += ws_g * S_t;
// one __syncthreads per tile (drains B DMA only). Per-nt epilogue writes
// its 64 KB output slab -> output store spread across the kernel.
// Math identical to r9/r14 (same quant formula, same i8 MFMA group combine).
__global__ __launch_bounds__(256) void gemm_panel_kernel(
    const float* __restrict__ x,
    const int8_t* __restrict__ Wd,
    const float* __restrict__ w_scale,
    const float* __restrict__ bias_f,
    const float* __restrict__ in_scale_p, const int* __restrict__ in_zp_p,
    const float* __restrict__ out_scale_p, const int* __restrict__ out_zp_p,
    float* __restrict__ out)
{
    __shared__ __align__(16) int8_t Apanel[P_BM * K_DIM];    // 128 KB
    __shared__ __align__(16) int8_t Bbuf[2][T_BN * T_BK];    // 16 KB
    __shared__ float WS[NGRP * T_BN];                         // 4 KB [g][n_local]

    const int t = threadIdx.x;
    const int mt = blockIdx.x;          // 0..511 (one per 128-row panel)
    const int m0 = mt * P_BM;

    const int wid = t >> 6;
    const int lane = t & 63;
    const int wr = wid >> 1, wc = wid & 1;     // 2x2 waves, each owns 64x64
    const int lrow = lane & 15;
    const int kslot = lane >> 4;               // 16B k-chunk
    const int koffB = ((kslot ^ ((lrow >> 1) & 3)) << 4);  // B swizzle (r2-r15)
    const int widoff = wid * 1024;

    const float in_s = in_scale_p[0];
    const float inv = 1.0f / in_s;
    const float izp = (float)in_zp_p[0];

    // ---- phase 1: quantize x panel into LDS (8192 16B chunks, 32/thread) ----
#pragma unroll 4
    for (int i = 0; i < 32; ++i) {
        const int c = i * 256 + t;
        const int r = c >> 6;                  // row 0..127
        const int s = c & 63;                  // 16B chunk within row
        const float* src = x + (size_t)(m0 + r) * K_DIM + s * 16;
        union { int4 u; int8_t b[16]; } pk;
#pragma unroll
        for (int q4 = 0; q4 < 4; ++q4) {
            const float4 v = *reinterpret_cast<const float4*>(src + q4 * 4);
            const float vv[4] = {v.x, v.y, v.z, v.w};
#pragma unroll
            for (int e = 0; e < 4; ++e) {
                float q = rintf(vv[e] * inv) + izp;     // RNE matches jnp.round
                q = fminf(fmaxf(q, -128.0f), 127.0f);
                pk.b[q4 * 4 + e] = (int8_t)(q - izp);
            }
        }
        *reinterpret_cast<int4*>(Apanel + r * 1024 + ((s * 16) ^ ((r & 7) << 4))) = pk.u;
    }

    // B staging via global_load_lds, pre-swizzled source (r9 verbatim)
    auto stageB = [&](int8_t* dst, const int8_t* Bbase, int kt) {
        const int k0 = kt * T_BK;
#pragma unroll
        for (int j = 0; j < 2; ++j) {
            const int c = j * 256 + t;                 // 16B chunk id 0..511
            const int r = c >> 2;                      // row 0..127
            const int sl = (c & 3) ^ ((r >> 1) & 3);
            const int8_t* src = Bbase + (size_t)r * K_DIM + k0 + sl * 16;
            __builtin_amdgcn_global_load_lds(
                (const __attribute__((address_space(1))) void*)src,
                (__attribute__((address_space(3))) void*)(dst + j * 4096 + widoff),
                16, 0, 0);
        }
    };

    const float out_s = out_scale_p[0];
    const float out_inv = 1.0f / out_s;
    const float ozp = (float)out_zp_p[0];
    const int col = lane & 15;
    const int rgrp = lane >> 4;

#pragma unroll 1
    for (int nt = 0; nt < NNT; ++nt) {
        const int n0 = nt * T_BN;
        const int8_t* Bbase = Wd + (size_t)n0 * K_DIM;

        // WS for this nt (reads of previous nt's WS all completed at the
        // last tile barrier of the previous pass)
        {
            const int nl = t >> 1;
            const int g4 = (t & 1) * 4;
            const float4 wv = *reinterpret_cast<const float4*>(
                w_scale + (size_t)(n0 + nl) * NGRP + g4);
            WS[(g4 + 0) * T_BN + nl] = wv.x;
            WS[(g4 + 1) * T_BN + nl] = wv.y;
            WS[(g4 + 2) * T_BN + nl] = wv.z;
            WS[(g4 + 3) * T_BN + nl] = wv.w;
        }
        stageB(&Bbuf[0][0], Bbase, 0);
        __syncthreads();   // drains: panel writes (nt=0), WS writes, B DMA

        f32x4 facc[4][4];
#pragma unroll
        for (int mi = 0; mi < 4; ++mi)
#pragma unroll
            for (int ni = 0; ni < 4; ++ni)
                facc[mi][ni] = (f32x4){0.f, 0.f, 0.f, 0.f};

        int buf = 0;
#pragma unroll 1
        for (int kt = 0; kt < T_NKT; ++kt) {
            if (kt + 1 < T_NKT)
                stageB(&Bbuf[buf ^ 1][0], Bbase, kt + 1);

            ix4 af[4], bfr[4];
#pragma unroll
            for (int i = 0; i < 4; ++i) {
                const int arow = wr * 64 + i * 16 + lrow;
                const int bo = (kt * 64 + kslot * 16) ^ ((arow & 7) << 4);
                af[i] = *reinterpret_cast<const ix4*>(Apanel + arow * 1024 + bo);
            }
#pragma unroll
            for (int i = 0; i < 4; ++i) {
                const int brow = wc * 64 + i * 16 + lrow;
                bfr[i] = *reinterpret_cast<const ix4*>(&Bbuf[buf][brow * 64 + koffB]);
            }

            const int g = kt >> 1;
            float wsv[4];
#pragma unroll
            for (int ni = 0; ni < 4; ++ni)
                wsv[ni] = WS[g * T_BN + wc * 64 + ni * 16 + lrow];

#pragma unroll
            for (int mi = 0; mi < 4; ++mi) {
                ix4 s0 = __builtin_amdgcn_mfma_i32_16x16x64_i8(af[mi], bfr[0], (ix4){0,0,0,0}, 0, 0, 0);
                ix4 s1 = __builtin_amdgcn_mfma_i32_16x16x64_i8(af[mi], bfr[1], (ix4){0,0,0,0}, 0, 0, 0);
                ix4 s2 = __builtin_amdgcn_mfma_i32_16x16x64_i8(af[mi], bfr[2], (ix4){0,0,0,0}, 0, 0, 0);
                ix4 s3 = __builtin_amdgcn_mfma_i32_16x16x64_i8(af[mi], bfr[3], (ix4){0,0,0,0}, 0, 0, 0);
#pragma unroll
                for (int e = 0; e < 4; ++e) {
                    facc[mi][0][e] += wsv[0] * (float)s0[e];
                    facc[mi][1][e] += wsv[1] * (float)s1[e];
                    facc[mi][2][e] += wsv[2] * (float)s2[e];
                    facc[mi][3][e] += wsv[3] * (float)s3[e];
                }
            }

            __syncthreads();
            buf ^= 1;
        }

        // ---- per-nt epilogue: v = in_s * facc + bias; output fake-quant ----
#pragma unroll
        for (int ni = 0; ni < 4; ++ni) {
            const int n = n0 + wc * 64 + ni * 16 + col;
            const float bv = bias_f[n];
#pragma unroll
            for (int mi = 0; mi < 4; ++mi) {
#pragma unroll
                for (int j = 0; j < 4; ++j) {
                    const int m = m0 + wr * 64 + mi * 16 + rgrp * 4 + j;
                    float v = in_s * facc[mi][ni][j] + bv;
                    float q = rintf(v * out_inv) + ozp;
                    q = fminf(fmaxf(q, -128.0f), 127.0f);
                    out[(size_t)m * N_DIM + n] = (q - ozp) * out_s;
                }
            }
        }
        // no barrier needed: next pass's WS/B writes are ordered by the
        // next __syncthreads before any read
    }
}

extern "C" void kernel_launch(void* const* d_in, const int* in_sizes, int n_in,
                              void* d_out, int out_size, void* d_ws, size_t ws_size,
                              hipStream_t stream) {
    const float* x          = (const float*)d_in[0];
    const int*   w_q        = (const int*)d_in[1];
    const float* w_scale    = (const float*)d_in[2];
    const int*   w_zp       = (const int*)d_in[3];
    const int*   bias_q     = (const int*)d_in[4];
    const float* bias_scale = (const float*)d_in[5];
    const float* in_scale   = (const float*)d_in[6];
    const int*   in_zp      = (const int*)d_in[7];
    const float* out_scale  = (const float*)d_in[8];
    const int*   out_zp     = (const int*)d_in[9];

    int8_t* Wd    = (int8_t*)d_ws;                                   // 1 MB
    float* bias_f = (float*)((char*)d_ws + (size_t)N_DIM * K_DIM);   // 4 KB

    prep_wd_kernel<<<N_DIM, 256, 0, stream>>>(w_q, w_zp, bias_q, bias_scale, Wd, bias_f);

    const int grid = M_DIM / P_BM;    // 512
    gemm_panel_kernel<<<grid, 256, 0, stream>>>(x, Wd, w_scale, bias_f,
                                                in_scale, in_zp, out_scale, out_zp,
                                                (float*)d_out);
}

// Round 17
// 220.762 us; speedup vs baseline: 1.4916x; 1.4916x over previous
//
#include <hip/hip_runtime.h>
#include <hip/hip_bf16.h>
#include <stdint.h>

// Problem constants (B=8, S=8192, K=1024, N=1024, G=128)
#define M_DIM 65536
#define K_DIM 1024
#define N_DIM 1024
#define NGRP  8

// 128x128 i8 GEMM, BK=64, static dbuf (r9 verbatim — proven 154us)
#define T_BM 128
#define T_BN 128
#define T_BK 64
#define T_NKT (K_DIM / T_BK)    // 16

#define PREP_WD_BLOCKS 1024
#define PREP_X8_BLOCKS ((M_DIM * (size_t)K_DIM) / (256 * 16))   // 16384

typedef float f32x4 __attribute__((ext_vector_type(4)));
typedef int   ix4   __attribute__((ext_vector_type(4)));

// ---------------- merged prep: wd (blocks 0..1023) + x8 quant (rest) ----------------
__global__ __launch_bounds__(256) void prep_all_kernel(
    const float* __restrict__ x,
    const int* __restrict__ w_q,
    const int* __restrict__ w_zp,
    const int* __restrict__ bias_q,
    const float* __restrict__ bias_scale,
    const float* __restrict__ in_scale_p, const int* __restrict__ in_zp_p,
    int8_t* __restrict__ Wd,
    float* __restrict__ bias_f,
    int8_t* __restrict__ Xq)
{
    const int t = threadIdx.x;
    if (blockIdx.x < PREP_WD_BLOCKS) {
        const int n = blockIdx.x;
        const int k0 = t * 4;
        const int g = k0 >> 7;
        const int zp = w_zp[n * NGRP + g];
        const int4 wq = *reinterpret_cast<const int4*>(w_q + (size_t)n * K_DIM + k0);
        union { int u; int8_t b[4]; } pk;
        pk.b[0] = (int8_t)(wq.x - zp);
        pk.b[1] = (int8_t)(wq.y - zp);
        pk.b[2] = (int8_t)(wq.z - zp);
        pk.b[3] = (int8_t)(wq.w - zp);
        *reinterpret_cast<int*>(Wd + (size_t)n * K_DIM + k0) = pk.u;
        if (t == 0) bias_f[n] = ((float)bias_q[n] - 128.0f) * bias_scale[n];
        return;
    }
    const float s = in_scale_p[0];
    const float inv = 1.0f / s;
    const float zp = (float)in_zp_p[0];
    const size_t i = ((size_t)(blockIdx.x - PREP_WD_BLOCKS) * 256 + t) * 16;
    float vv[16];
#pragma unroll
    for (int c = 0; c < 4; ++c) {
        const float4 v = *reinterpret_cast<const float4*>(x + i + c * 4);
        vv[c * 4 + 0] = v.x; vv[c * 4 + 1] = v.y;
        vv[c * 4 + 2] = v.z; vv[c * 4 + 3] = v.w;
    }
    union { int4 u; int8_t b[16]; } pk;
#pragma unroll
    for (int e = 0; e < 16; ++e) {
        float q = rintf(vv[e] * inv) + zp;       // RNE matches jnp.round
        q = fminf(fmaxf(q, -128.0f), 127.0f);
        pk.b[e] = (int8_t)(q - zp);
    }
    *reinterpret_cast<int4*>(Xq + i) = pk.u;
}

// ---------------- 128x128 i8 GEMM (round-9 kernel, verbatim) ----------------
// 256 thr = 4 waves (2x2), wave owns 64x64. Static dbuf, plain __syncthreads.
// Per K-64 tile: stage next buf (4 gload_lds/thread), read frags (8 b128),
// 16 MFMA i8 -> i32 (C=0, independent), exact per-tile group combine
// facc += ws_g * S_t, one __syncthreads (drains vmcnt+lgkm; WAR/RAW covered).
// Measured r9/r14: gemm ~154us, absmax 0.15625. All structural variants
// lost: ring+vmcnt (r10 +64us), group-pair acc (r11 +46), fused quant
// (r12 +278), direct-A (r13 +84), 2-wave blocks (r15 +19), panel-A (r16 +216).
__global__ __launch_bounds__(256, 3) void gemm128_i8_kernel(
    const int8_t* __restrict__ Xq,
    const int8_t* __restrict__ Wd,
    const float* __restrict__ w_scale,
    const float* __restrict__ bias_f,
    const float* __restrict__ in_scale_p,
    const float* __restrict__ out_scale_p, const int* __restrict__ out_zp_p,
    float* __restrict__ out)
{
    __shared__ __align__(16) int8_t Abuf[2][T_BM * T_BK];   // 2 x 8 KB
    __shared__ __align__(16) int8_t Bbuf[2][T_BN * T_BK];   // 2 x 8 KB
    __shared__ float WS[NGRP * T_BN];                        // 4 KB [g][n_local]

    const int t = threadIdx.x;
    // bijective XCD swizzle: grid=4096, 8 XCDs, 512 blocks/XCD;
    // consecutive local bids share the A panel (mt) across nt=0..7.
    const int bid = (blockIdx.x & 7) * 512 + (blockIdx.x >> 3);
    const int nt = bid & 7;
    const int mt = bid >> 3;
    const int m0 = mt * T_BM;
    const int n0 = nt * T_BN;

    const int wid = t >> 6;
    const int lane = t & 63;
    const int wr = wid >> 1, wc = wid & 1;     // 2x2 waves, each owns 64x64
    const int lrow = lane & 15;
    const int kslot = lane >> 4;               // 16B k-chunk within 64B row
    const int koff = ((kslot ^ ((lrow >> 1) & 3)) << 4);   // XOR swizzle (0-conflict)
    const int widoff = wid * 1024;

    const int8_t* Abase = Xq + (size_t)m0 * K_DIM;
    const int8_t* Bbase = Wd + (size_t)n0 * K_DIM;

    // ---- preload w_scale panel [g][n_local] (drained by prologue barrier) ----
    {
        const int nl = t >> 1;                 // 0..127
        const int g4 = (t & 1) * 4;
        const float4 wv = *reinterpret_cast<const float4*>(
            w_scale + (size_t)(n0 + nl) * NGRP + g4);
        WS[(g4 + 0) * T_BN + nl] = wv.x;
        WS[(g4 + 1) * T_BN + nl] = wv.y;
        WS[(g4 + 2) * T_BN + nl] = wv.z;
        WS[(g4 + 3) * T_BN + nl] = wv.w;
    }

    // stage one 128x64B tile (512 chunks, 2/thread), pre-swizzled source
    auto stage = [&](int8_t* dst, const int8_t* panel, int kt) {
        const int k0 = kt * T_BK;
#pragma unroll
        for (int j = 0; j < 2; ++j) {
            const int c = j * 256 + t;                 // 16B chunk id 0..511
            const int r = c >> 2;                      // row 0..127
            const int sl = (c & 3) ^ ((r >> 1) & 3);   // logical k-slot at phys slot
            const int8_t* src = panel + (size_t)r * K_DIM + k0 + sl * 16;
            __builtin_amdgcn_global_load_lds(
                (const __attribute__((address_space(1))) void*)src,
                (__attribute__((address_space(3))) void*)(dst + j * 4096 + widoff),
                16, 0, 0);
        }
    };

    f32x4 facc[4][4];
#pragma unroll
    for (int mi = 0; mi < 4; ++mi)
#pragma unroll
        for (int ni = 0; ni < 4; ++ni)
            facc[mi][ni] = (f32x4){0.f, 0.f, 0.f, 0.f};

    // prologue: stage tile 0 into buf 0 (WS + DMA drained by syncthreads)
    stage(&Abuf[0][0], Abase, 0);
    stage(&Bbuf[0][0], Bbase, 0);
    __syncthreads();

    int buf = 0;
#pragma unroll 1
    for (int kt = 0; kt < T_NKT; ++kt) {
        if (kt + 1 < T_NKT) {
            stage(&Abuf[buf ^ 1][0], Abase, kt + 1);
            stage(&Bbuf[buf ^ 1][0], Bbase, kt + 1);
        }

        ix4 af[4], bfr[4];
#pragma unroll
        for (int i = 0; i < 4; ++i) {
            const int arow = wr * 64 + i * 16 + lrow;
            af[i] = *reinterpret_cast<const ix4*>(&Abuf[buf][arow * 64 + koff]);
        }
#pragma unroll
        for (int i = 0; i < 4; ++i) {
            const int brow = wc * 64 + i * 16 + lrow;
            bfr[i] = *reinterpret_cast<const ix4*>(&Bbuf[buf][brow * 64 + koff]);
        }

        const int g = kt >> 1;
        float wsv[4];
#pragma unroll
        for (int ni = 0; ni < 4; ++ni)
            wsv[ni] = WS[g * T_BN + wc * 64 + ni * 16 + lrow];

#pragma unroll
        for (int mi = 0; mi < 4; ++mi) {
            ix4 s0 = __builtin_amdgcn_mfma_i32_16x16x64_i8(af[mi], bfr[0], (ix4){0,0,0,0}, 0, 0, 0);
            ix4 s1 = __builtin_amdgcn_mfma_i32_16x16x64_i8(af[mi], bfr[1], (ix4){0,0,0,0}, 0, 0, 0);
            ix4 s2 = __builtin_amdgcn_mfma_i32_16x16x64_i8(af[mi], bfr[2], (ix4){0,0,0,0}, 0, 0, 0);
            ix4 s3 = __builtin_amdgcn_mfma_i32_16x16x64_i8(af[mi], bfr[3], (ix4){0,0,0,0}, 0, 0, 0);
#pragma unroll
            for (int e = 0; e < 4; ++e) {
                facc[mi][0][e] += wsv[0] * (float)s0[e];
                facc[mi][1][e] += wsv[1] * (float)s1[e];
                facc[mi][2][e] += wsv[2] * (float)s2[e];
                facc[mi][3][e] += wsv[3] * (float)s3[e];
            }
        }

        __syncthreads();
        buf ^= 1;
    }

    // ---- epilogue: v = in_s * facc + bias; output fake-quant ----
    const float in_s  = in_scale_p[0];
    const float out_s = out_scale_p[0];
    const float out_inv = 1.0f / out_s;
    const float ozp = (float)out_zp_p[0];
    const int col = lane & 15;
    const int rgrp = lane >> 4;
#pragma unroll
    for (int ni = 0; ni < 4; ++ni) {
        const int n = n0 + wc * 64 + ni * 16 + col;
        const float bv = bias_f[n];
#pragma unroll
        for (int mi = 0; mi < 4; ++mi) {
#pragma unroll
            for (int j = 0; j < 4; ++j) {
                const int m = m0 + wr * 64 + mi * 16 + rgrp * 4 + j;
                float v = in_s * facc[mi][ni][j] + bv;
                float q = rintf(v * out_inv) + ozp;
                q = fminf(fmaxf(q, -128.0f), 127.0f);
                out[(size_t)m * N_DIM + n] = (q - ozp) * out_s;
            }
        }
    }
}

extern "C" void kernel_launch(void* const* d_in, const int* in_sizes, int n_in,
                              void* d_out, int out_size, void* d_ws, size_t ws_size,
                              hipStream_t stream) {
    const float* x          = (const float*)d_in[0];
    const int*   w_q        = (const int*)d_in[1];
    const float* w_scale    = (const float*)d_in[2];
    const int*   w_zp       = (const int*)d_in[3];
    const int*   bias_q     = (const int*)d_in[4];
    const float* bias_scale = (const float*)d_in[5];
    const float* in_scale   = (const float*)d_in[6];
    const int*   in_zp      = (const int*)d_in[7];
    const float* out_scale  = (const float*)d_in[8];
    const int*   out_zp     = (const int*)d_in[9];

    const size_t xq8_bytes = (size_t)M_DIM * K_DIM;          // 67.1 MB
    const size_t wd_bytes  = (size_t)N_DIM * K_DIM;          // 1 MB

    int8_t* Xq8   = (int8_t*)d_ws;
    int8_t* Wd    = (int8_t*)((char*)d_ws + xq8_bytes);
    float* bias_f = (float*)((char*)d_ws + xq8_bytes + wd_bytes);

    prep_all_kernel<<<(int)(PREP_WD_BLOCKS + PREP_X8_BLOCKS), 256, 0, stream>>>(
        x, w_q, w_zp, bias_q, bias_scale, in_scale, in_zp, Wd, bias_f, Xq8);

    const int grid = (M_DIM / T_BM) * (N_DIM / T_BN);   // 512 * 8 = 4096
    gemm128_i8_kernel<<<grid, 256, 0, stream>>>(Xq8, Wd, w_scale, bias_f,
                                                in_scale, out_scale, out_zp,
                                                (float*)d_out);
}